// Round 1
// baseline (14708.107 us; speedup 1.0000x reference)
//
#include <hip/hip_runtime.h>

#define DEV __device__ __forceinline__

constexpr int NB  = 32;    // batch
constexpr int LXc = 256;   // decoder seq
constexpr int LYc = 128;   // encoder seq
constexpr int Dc  = 768;
constexpr int NH  = 12;
constexpr int FFc = 3072;

typedef unsigned short u16;
typedef float f32x4 __attribute__((ext_vector_type(4)));
typedef short s16x8 __attribute__((ext_vector_type(8)));

DEV u16 f2bf(float f) {                 // RNE f32 -> bf16 bits
  unsigned u = __float_as_uint(f);
  u += 0x7FFFu + ((u >> 16) & 1u);
  return (u16)(u >> 16);
}
DEV float bf2f(u16 w) { return __uint_as_float(((unsigned)w) << 16); }
DEV float ldf(const void* p, long long i, int isbf) {
  return isbf ? bf2f(((const u16*)p)[i]) : ((const float*)p)[i];
}

// ---------------- dtype detection ----------------
// If inputs are bf16, every 16-bit word of y decodes to a plausible bf16.
// If f32, only high half-words do (~55% total). Flag stored in ws.
__global__ void k_detect(const u16* y, int* flag) {
  if (threadIdx.x == 0) {
    int cnt = 0;
    for (int i = 0; i < 256; ++i) {
      u16 w = y[i];
      int e = (w >> 7) & 0xFF;
      if (e == 0 || (e >= 112 && e <= 140)) cnt++;
    }
    *flag = (cnt >= 200) ? 1 : 0;
  }
}

__global__ void k_ingest(const void* src, float* dst, long long n, const int* flag) {
  int isbf = *flag;
  long long i = (long long)blockIdx.x * blockDim.x + threadIdx.x;
  long long st = (long long)gridDim.x * blockDim.x;
  for (; i < n; i += st) dst[i] = ldf(src, i, isbf);
}

__global__ void k_emit(const float* ybuf, const float* xbuf, void* out,
                       const int* flag, long long ny, long long nt) {
  int isbf = *flag;
  long long i = (long long)blockIdx.x * blockDim.x + threadIdx.x;
  long long st = (long long)gridDim.x * blockDim.x;
  for (; i < nt; i += st) {
    float v = (i < ny) ? ybuf[i] : xbuf[i - ny];
    if (isbf) ((u16*)out)[i] = f2bf(v);
    else      ((float*)out)[i] = v;
  }
}

// ---------------- bbox cosine-sim + softmax ----------------
__global__ __launch_bounds__(256) void k_bboxsim(const void* bbox, const int* flag, float* sim) {
  int isbf = *flag;
  int b = blockIdx.x >> 8, i = blockIdx.x & 255;
  int j = threadIdx.x;
  long long base = (long long)b * LXc * 4;
  float a[4], c[4];
#pragma unroll
  for (int t = 0; t < 4; ++t) {
    a[t] = ldf(bbox, base + (long long)i * 4 + t, isbf);
    c[t] = ldf(bbox, base + (long long)j * 4 + t, isbf);
  }
  float dot = a[0]*c[0] + a[1]*c[1] + a[2]*c[2] + a[3]*c[3];
  float na  = sqrtf(a[0]*a[0] + a[1]*a[1] + a[2]*a[2] + a[3]*a[3]);
  float ncn = sqrtf(c[0]*c[0] + c[1]*c[1] + c[2]*c[2] + c[3]*c[3]);
  float v = dot / (na * ncn);
  __shared__ float r1[4], r2[4];
  float m = v;
  for (int o = 32; o; o >>= 1) m = fmaxf(m, __shfl_xor(m, o));
  if ((threadIdx.x & 63) == 0) r1[threadIdx.x >> 6] = m;
  __syncthreads();
  m = fmaxf(fmaxf(r1[0], r1[1]), fmaxf(r1[2], r1[3]));
  float e = __expf(v - m);
  float s = e;
  for (int o = 32; o; o >>= 1) s += __shfl_xor(s, o);
  if ((threadIdx.x & 63) == 0) r2[threadIdx.x >> 6] = s;
  __syncthreads();
  s = r2[0] + r2[1] + r2[2] + r2[3];
  sim[((long long)b * LXc + i) * LXc + j] = e / s;
}

// ---------------- row softmax (one wave per row, Lk<=256) ----------------
__global__ __launch_bounds__(256) void k_softmax(float* S, int Lk, long long nrows) {
  long long row = (long long)blockIdx.x * 4 + (threadIdx.x >> 6);
  int lane = threadIdx.x & 63;
  if (row >= nrows) return;
  float* r = S + row * Lk;
  int nv = Lk >> 6;
  float v[4];
  float mx = -3.0e38f;
  for (int i = 0; i < nv; ++i) { v[i] = r[i * 64 + lane]; mx = fmaxf(mx, v[i]); }
  for (int o = 32; o; o >>= 1) mx = fmaxf(mx, __shfl_xor(mx, o));
  float s = 0.f;
  for (int i = 0; i < nv; ++i) { v[i] = __expf(v[i] - mx); s += v[i]; }
  for (int o = 32; o; o >>= 1) s += __shfl_xor(s, o);
  float inv = 1.0f / s;
  for (int i = 0; i < nv; ++i) r[i * 64 + lane] = v[i] * inv;
}

// ---------------- residual + layernorm (block per row, D=768) ----------------
__global__ __launch_bounds__(256) void k_lnres(float* cur, const float* delta,
                                               const void* g, long long gOff,
                                               const void* bb, long long bOff,
                                               const int* flag) {
  int isbf = *flag;
  long long row = blockIdx.x;
  float* xr = cur + row * Dc;
  const float* dr = delta + row * Dc;
  int t = threadIdx.x;
  float v[3];
  float s = 0.f;
#pragma unroll
  for (int i = 0; i < 3; ++i) { int c = t + i * 256; v[i] = xr[c] + dr[c]; s += v[i]; }
  __shared__ float r1[4], r2[4];
  for (int o = 32; o; o >>= 1) s += __shfl_xor(s, o);
  if ((t & 63) == 0) r1[t >> 6] = s;
  __syncthreads();
  float mean = (r1[0] + r1[1] + r1[2] + r1[3]) * (1.0f / 768.0f);
  float s2 = 0.f;
#pragma unroll
  for (int i = 0; i < 3; ++i) { float d = v[i] - mean; s2 += d * d; }
  for (int o = 32; o; o >>= 1) s2 += __shfl_xor(s2, o);
  if ((t & 63) == 0) r2[t >> 6] = s2;
  __syncthreads();
  float var = (r2[0] + r2[1] + r2[2] + r2[3]) * (1.0f / 768.0f);
  float rstd = rsqrtf(var + 1e-6f);
#pragma unroll
  for (int i = 0; i < 3; ++i) {
    int c = t + i * 256;
    xr[c] = ldf(g, gOff + c, isbf) * (v[i] - mean) * rstd + ldf(bb, bOff + c, isbf);
  }
}

// ---------------- generic batched MFMA GEMM ----------------
// C[z] = act(scale * A[z] @ op(W[z]) + bias), all dims divide tiles exactly.
// z -> (b = z/Hdim, h = z%Hdim); offsets: A += b*sAb + h*sAh (f32 elements),
// W element offset wOff + b*sWb + h*sWh (dtype per wRaw/flag), C += b*sCb + h*sCh.
struct GemmP {
  const float* A; long long lda, sAb, sAh;
  const void* W;  long long wOff, ldw, sWb, sWh;
  const void* bias; long long bOff;
  float* C; long long ldc, sCb, sCh;
  int Hdim; float scale; int act, transW, wRaw;
};

template<int BM, int BN>
__global__ __launch_bounds__(256, 2) void gemm_k(GemmP p, const int* dflag, int M, int N, int K) {
  constexpr int BK = 64, LDP = BK + 8;           // +8 bf16 pad vs bank conflicts
  __shared__ __align__(16) u16 Al[BM][LDP];
  __shared__ __align__(16) u16 Bl[BN][LDP];
  const int tid = threadIdx.x;
  const int z = blockIdx.z;
  const int b = z / p.Hdim, h = z % p.Hdim;
  const float* A = p.A + (long long)b * p.sAb + (long long)h * p.sAh;
  const long long wBase = p.wOff + (long long)b * p.sWb + (long long)h * p.sWh;
  float* C = p.C + (long long)b * p.sCb + (long long)h * p.sCh;
  const int isbf = p.wRaw ? *dflag : 0;
  const int m0 = blockIdx.y * BM, n0 = blockIdx.x * BN;
  const int wid = tid >> 6, lane = tid & 63;
  const int wr = wid >> 1, wc = wid & 1;
  constexpr int FM = BM / 32, FN = BN / 32;
  f32x4 acc[FM][FN] = {};

  for (int k0 = 0; k0 < K; k0 += BK) {
    // ---- stage A (always f32 in ws) ----
#pragma unroll
    for (int it = 0; it < BM * BK / 1024; ++it) {
      int idx = (it * 256 + tid) * 4;
      int r = idx >> 6, k = idx & 63;
      float4 v = *(const float4*)(A + (long long)(m0 + r) * p.lda + (k0 + k));
      union { u16 u[4]; uint2 d; } pk;
      pk.u[0] = f2bf(v.x); pk.u[1] = f2bf(v.y); pk.u[2] = f2bf(v.z); pk.u[3] = f2bf(v.w);
      *(uint2*)&Al[r][k] = pk.d;
    }
    // ---- stage B as [n][k] ----
    if (p.transW) {   // W stored [N][K] row-major, f32 ws only (QK^T path)
      const float* Wf = (const float*)p.W;
#pragma unroll
      for (int it = 0; it < BN * BK / 1024; ++it) {
        int idx = (it * 256 + tid) * 4;
        int r = idx >> 6, k = idx & 63;
        float4 v = *(const float4*)(Wf + wBase + (long long)(n0 + r) * p.ldw + (k0 + k));
        union { u16 u[4]; uint2 d; } pk;
        pk.u[0] = f2bf(v.x); pk.u[1] = f2bf(v.y); pk.u[2] = f2bf(v.z); pk.u[3] = f2bf(v.w);
        *(uint2*)&Bl[r][k] = pk.d;
      }
    } else {          // W stored [K][N]; transpose during staging
      const int n = tid % BN;
      const int kb = (tid / BN) * (BN / 4);
#pragma unroll
      for (int c = 0; c < BN / 32; ++c) {
        union { u16 u[8]; uint4 d; } pk;
#pragma unroll
        for (int j = 0; j < 8; ++j) {
          int kk = kb + c * 8 + j;
          long long gaddr = wBase + (long long)(k0 + kk) * p.ldw + (n0 + n);
          float fv = isbf ? bf2f(((const u16*)p.W)[gaddr]) : ((const float*)p.W)[gaddr];
          pk.u[j] = f2bf(fv);
        }
        *(uint4*)&Bl[n][kb + c * 8] = pk.d;
      }
    }
    __syncthreads();
    // ---- MFMA ----
#pragma unroll
    for (int ks = 0; ks < BK / 32; ++ks) {
      s16x8 af[FM], bfr[FN];
      const int rl = lane & 15, kc = ks * 32 + (lane >> 4) * 8;
#pragma unroll
      for (int i = 0; i < FM; ++i) af[i]  = *(const s16x8*)&Al[wr * (BM / 2) + i * 16 + rl][kc];
#pragma unroll
      for (int j = 0; j < FN; ++j) bfr[j] = *(const s16x8*)&Bl[wc * (BN / 2) + j * 16 + rl][kc];
#pragma unroll
      for (int i = 0; i < FM; ++i)
#pragma unroll
        for (int j = 0; j < FN; ++j)
          acc[i][j] = __builtin_amdgcn_mfma_f32_16x16x32_bf16(af[i], bfr[j], acc[i][j], 0, 0, 0);
    }
    __syncthreads();
  }
  // ---- epilogue: scale, bias, relu, f32 store ----
#pragma unroll
  for (int j = 0; j < FN; ++j) {
    int col = n0 + wc * (BN / 2) + j * 16 + (lane & 15);
    float bv = 0.f;
    if (p.bias) bv = isbf ? bf2f(((const u16*)p.bias)[p.bOff + col])
                          : ((const float*)p.bias)[p.bOff + col];
#pragma unroll
    for (int i = 0; i < FM; ++i) {
      int row0 = m0 + wr * (BM / 2) + i * 16 + (lane >> 4) * 4;
#pragma unroll
      for (int e = 0; e < 4; ++e) {
        float v = acc[i][j][e] * p.scale + bv;
        if (p.act) v = fmaxf(v, 0.f);
        C[(long long)(row0 + e) * p.ldc + col] = v;
      }
    }
  }
}

// ---------------- host-side launch helpers ----------------
static void g_plain(const float* A, int M, const void* W, long long wOff,
                    const void* bias, long long bOff, float* C, int N, int K,
                    int act, const int* flag, hipStream_t st) {
  GemmP p{};
  p.A = A; p.lda = K; p.sAb = 0; p.sAh = 0;
  p.W = W; p.wOff = wOff; p.ldw = N; p.sWb = 0; p.sWh = 0;
  p.bias = bias; p.bOff = bOff;
  p.C = C; p.ldc = N; p.sCb = 0; p.sCh = 0;
  p.Hdim = 1; p.scale = 1.0f; p.act = act; p.transW = 0; p.wRaw = 1;
  dim3 grid(N / 128, M / 128, 1);
  gemm_k<128, 128><<<grid, 256, 0, st>>>(p, flag, M, N, K);
}

static void g_scores(const float* Q, const float* Kb, int Lq, int Lk, float* S,
                     const int* flag, hipStream_t st) {
  GemmP p{};
  p.A = Q; p.lda = Dc; p.sAb = (long long)Lq * Dc; p.sAh = 64;
  p.W = Kb; p.wOff = 0; p.ldw = Dc; p.sWb = (long long)Lk * Dc; p.sWh = 64;
  p.bias = nullptr; p.bOff = 0;
  p.C = S; p.ldc = Lk; p.sCb = (long long)NH * Lq * Lk; p.sCh = (long long)Lq * Lk;
  p.Hdim = NH; p.scale = 0.125f; p.act = 0; p.transW = 1; p.wRaw = 0;
  dim3 grid(Lk / 128, Lq / 128, NB * NH);
  gemm_k<128, 128><<<grid, 256, 0, st>>>(p, flag, Lq, Lk, 64);
}

static void g_pv(const float* S, const float* V, int Lq, int Lk, float* AO,
                 const int* flag, hipStream_t st) {
  GemmP p{};
  p.A = S; p.lda = Lk; p.sAb = (long long)NH * Lq * Lk; p.sAh = (long long)Lq * Lk;
  p.W = V; p.wOff = 0; p.ldw = Dc; p.sWb = (long long)Lk * Dc; p.sWh = 64;
  p.bias = nullptr; p.bOff = 0;
  p.C = AO; p.ldc = Dc; p.sCb = (long long)Lq * Dc; p.sCh = 64;
  p.Hdim = NH; p.scale = 1.0f; p.act = 0; p.transW = 0; p.wRaw = 0;
  dim3 grid(1, Lq / 128, NB * NH);
  gemm_k<128, 64><<<grid, 256, 0, st>>>(p, flag, Lq, 64, Lk);
}

static void g_rel(const float* sim, const float* AO, float* AO2,
                  const int* flag, hipStream_t st) {
  GemmP p{};
  p.A = sim; p.lda = LXc; p.sAb = (long long)LXc * LXc; p.sAh = 0;
  p.W = AO; p.wOff = 0; p.ldw = Dc; p.sWb = (long long)LXc * Dc; p.sWh = 0;
  p.bias = nullptr; p.bOff = 0;
  p.C = AO2; p.ldc = Dc; p.sCb = (long long)LXc * Dc; p.sCh = 0;
  p.Hdim = 1; p.scale = 1.0f; p.act = 0; p.transW = 0; p.wRaw = 0;
  dim3 grid(Dc / 128, LXc / 128, NB);
  gemm_k<128, 128><<<grid, 256, 0, st>>>(p, flag, LXc, Dc, LXc);
}

extern "C" void kernel_launch(void* const* d_in, const int* in_sizes, int n_in,
                              void* d_out, int out_size, void* d_ws, size_t ws_size,
                              hipStream_t stream) {
  const void* y_in  = d_in[0];
  const void* x_in  = d_in[1];
  const void* bbox  = d_in[5];
  const void* enc_aw = d_in[6];  const void* enc_ab = d_in[7];
  const void* enc_w1 = d_in[8];  const void* enc_b1 = d_in[9];
  const void* enc_w2 = d_in[10]; const void* enc_b2 = d_in[11];
  const void* enc_lg = d_in[12]; const void* enc_lb = d_in[13];
  const void* dec_aw = d_in[14]; const void* dec_ab = d_in[15];
  const void* dec_w1 = d_in[16]; const void* dec_b1 = d_in[17];
  const void* dec_w2 = d_in[18]; const void* dec_b2 = d_in[19];
  const void* dec_lg = d_in[20]; const void* dec_lb = d_in[21];

  int* flag = (int*)d_ws;
  float* F = (float*)((char*)d_ws + 256);
  const long long NYt = (long long)NB * LYc * Dc;   // 3,145,728
  const long long NXt = (long long)NB * LXc * Dc;   // 6,291,456
  float* cur_y = F;
  float* cur_x = cur_y + NYt;
  float* simb  = cur_x + NXt;
  float* qb    = simb + (long long)NB * LXc * LXc;
  float* kbuf  = qb + NXt;
  float* vbuf  = kbuf + NXt;
  float* ao    = vbuf + NXt;
  float* ao2   = ao + NXt;
  float* big   = ao2 + NXt;                          // scores / ffn scratch (100.7 MB)

  k_detect<<<1, 64, 0, stream>>>((const u16*)y_in, flag);
  k_ingest<<<1024, 256, 0, stream>>>(y_in, cur_y, NYt, flag);
  k_ingest<<<1024, 256, 0, stream>>>(x_in, cur_x, NXt, flag);
  k_bboxsim<<<NB * LXc, 256, 0, stream>>>(bbox, flag, simb);

  const long long DD = (long long)Dc * Dc;

  for (int i = 0; i < 6; ++i) {   // encoder
    int M = NB * LYc;
    g_plain(cur_y, M, enc_aw, (long long)(i * 4 + 0) * DD, enc_ab, (long long)(i * 4 + 0) * Dc, qb,   Dc, Dc, 0, flag, stream);
    g_plain(cur_y, M, enc_aw, (long long)(i * 4 + 1) * DD, enc_ab, (long long)(i * 4 + 1) * Dc, kbuf, Dc, Dc, 0, flag, stream);
    g_plain(cur_y, M, enc_aw, (long long)(i * 4 + 2) * DD, enc_ab, (long long)(i * 4 + 2) * Dc, vbuf, Dc, Dc, 0, flag, stream);
    g_scores(qb, kbuf, LYc, LYc, big, flag, stream);
    k_softmax<<<(NB * NH * LYc) / 4, 256, 0, stream>>>(big, LYc, (long long)NB * NH * LYc);
    g_pv(big, vbuf, LYc, LYc, ao, flag, stream);
    g_plain(ao, M, enc_aw, (long long)(i * 4 + 3) * DD, enc_ab, (long long)(i * 4 + 3) * Dc, qb, Dc, Dc, 0, flag, stream);
    k_lnres<<<M, 256, 0, stream>>>(cur_y, qb, enc_lg, (long long)(i * 2 + 0) * Dc, enc_lb, (long long)(i * 2 + 0) * Dc, flag);
    g_plain(cur_y, M, enc_w1, (long long)i * Dc * FFc, enc_b1, (long long)i * FFc, big, FFc, Dc, 1, flag, stream);
    g_plain(big,   M, enc_w2, (long long)i * FFc * Dc, enc_b2, (long long)i * Dc,  qb,  Dc, FFc, 0, flag, stream);
    k_lnres<<<M, 256, 0, stream>>>(cur_y, qb, enc_lg, (long long)(i * 2 + 1) * Dc, enc_lb, (long long)(i * 2 + 1) * Dc, flag);
  }

  for (int i = 0; i < 6; ++i) {   // decoder
    int M = NB * LXc;
    // --- self attention (with rel) ---
    long long wo = (long long)(i * 2 + 0) * 4 * DD;
    long long bo = (long long)(i * 2 + 0) * 4 * Dc;
    g_plain(cur_x, M, dec_aw, wo + 0 * DD, dec_ab, bo + 0 * Dc, qb,   Dc, Dc, 0, flag, stream);
    g_plain(cur_x, M, dec_aw, wo + 1 * DD, dec_ab, bo + 1 * Dc, kbuf, Dc, Dc, 0, flag, stream);
    g_plain(cur_x, M, dec_aw, wo + 2 * DD, dec_ab, bo + 2 * Dc, vbuf, Dc, Dc, 0, flag, stream);
    g_scores(qb, kbuf, LXc, LXc, big, flag, stream);
    k_softmax<<<(NB * NH * LXc) / 4, 256, 0, stream>>>(big, LXc, (long long)NB * NH * LXc);
    g_pv(big, vbuf, LXc, LXc, ao, flag, stream);
    g_rel(simb, ao, ao2, flag, stream);
    g_plain(ao2, M, dec_aw, wo + 3 * DD, dec_ab, bo + 3 * Dc, qb, Dc, Dc, 0, flag, stream);
    k_lnres<<<M, 256, 0, stream>>>(cur_x, qb, dec_lg, (long long)(i * 3 + 0) * Dc, dec_lb, (long long)(i * 3 + 0) * Dc, flag);
    // --- cross attention (q from x, k/v from y, with rel) ---
    wo = (long long)(i * 2 + 1) * 4 * DD;
    bo = (long long)(i * 2 + 1) * 4 * Dc;
    g_plain(cur_x, M,        dec_aw, wo + 0 * DD, dec_ab, bo + 0 * Dc, qb,   Dc, Dc, 0, flag, stream);
    g_plain(cur_y, NB * LYc, dec_aw, wo + 1 * DD, dec_ab, bo + 1 * Dc, kbuf, Dc, Dc, 0, flag, stream);
    g_plain(cur_y, NB * LYc, dec_aw, wo + 2 * DD, dec_ab, bo + 2 * Dc, vbuf, Dc, Dc, 0, flag, stream);
    g_scores(qb, kbuf, LXc, LYc, big, flag, stream);
    k_softmax<<<(NB * NH * LXc) / 4, 256, 0, stream>>>(big, LYc, (long long)NB * NH * LXc);
    g_pv(big, vbuf, LXc, LYc, ao, flag, stream);
    g_rel(simb, ao, ao2, flag, stream);
    g_plain(ao2, M, dec_aw, wo + 3 * DD, dec_ab, bo + 3 * Dc, qb, Dc, Dc, 0, flag, stream);
    k_lnres<<<M, 256, 0, stream>>>(cur_x, qb, dec_lg, (long long)(i * 3 + 1) * Dc, dec_lb, (long long)(i * 3 + 1) * Dc, flag);
    // --- ffn ---
    g_plain(cur_x, M, dec_w1, (long long)i * Dc * FFc, dec_b1, (long long)i * FFc, big, FFc, Dc, 1, flag, stream);
    g_plain(big,   M, dec_w2, (long long)i * FFc * Dc, dec_b2, (long long)i * Dc,  qb,  Dc, FFc, 0, flag, stream);
    k_lnres<<<M, 256, 0, stream>>>(cur_x, qb, dec_lg, (long long)(i * 3 + 2) * Dc, dec_lb, (long long)(i * 3 + 2) * Dc, flag);
  }

  k_emit<<<2048, 256, 0, stream>>>(cur_y, cur_x, d_out, flag, NYt, NYt + NXt);
}

// Round 2
// 4978.835 us; speedup vs baseline: 2.9541x; 2.9541x over previous
//
#include <hip/hip_runtime.h>

#define DEV __device__ __forceinline__

constexpr int NB  = 32;
constexpr int LXc = 256;
constexpr int LYc = 128;
constexpr int Dc  = 768;
constexpr int NH  = 12;
constexpr int FFc = 3072;

typedef unsigned short u16;
typedef float f32x4 __attribute__((ext_vector_type(4)));
typedef short s16x8 __attribute__((ext_vector_type(8)));

DEV u16 f2bf(float f) {
  unsigned u = __float_as_uint(f);
  u += 0x7FFFu + ((u >> 16) & 1u);
  return (u16)(u >> 16);
}
DEV float bf2f(u16 w) { return __uint_as_float(((unsigned)w) << 16); }
DEV float ldf(const void* p, long long i, int isbf) {
  return isbf ? bf2f(((const u16*)p)[i]) : ((const float*)p)[i];
}

DEV void gload16(const void* g, void* l) {
  __builtin_amdgcn_global_load_lds(
      (const __attribute__((address_space(1))) void*)g,
      (__attribute__((address_space(3))) void*)l, 16, 0, 0);
}

// ---------------- dtype detection ----------------
__global__ void k_detect(const u16* y, int* flag) {
  if (threadIdx.x == 0) {
    int cnt = 0;
    for (int i = 0; i < 256; ++i) {
      u16 w = y[i];
      int e = (w >> 7) & 0xFF;
      if (e == 0 || (e >= 112 && e <= 140)) cnt++;
    }
    *flag = (cnt >= 200) ? 1 : 0;
  }
}

// ---------------- ingest: raw -> f32 + bf16 mirror ----------------
__global__ void k_ingest2(const void* src, float* dst, u16* dstb, long long n, const int* flag) {
  int isbf = *flag;
  long long i = (long long)blockIdx.x * blockDim.x + threadIdx.x;
  long long st = (long long)gridDim.x * blockDim.x;
  for (; i < n; i += st) { float v = ldf(src, i, isbf); dst[i] = v; dstb[i] = f2bf(v); }
}

__global__ void k_cvt(const void* src, float* dst, long long n, const int* flag) {
  int isbf = *flag;
  long long i = (long long)blockIdx.x * blockDim.x + threadIdx.x;
  long long st = (long long)gridDim.x * blockDim.x;
  for (; i < n; i += st) dst[i] = ldf(src, i, isbf);
}

__global__ void k_emit(const float* ybuf, const float* xbuf, void* out,
                       const int* flag, long long ny, long long nt) {
  int isbf = *flag;
  long long i = (long long)blockIdx.x * blockDim.x + threadIdx.x;
  long long st = (long long)gridDim.x * blockDim.x;
  for (; i < nt; i += st) {
    float v = (i < ny) ? ybuf[i] : xbuf[i - ny];
    if (isbf) ((u16*)out)[i] = f2bf(v);
    else      ((float*)out)[i] = v;
  }
}

// ---------------- weight transpose+convert: [R][C] raw -> [C][R] bf16 ----------------
__global__ __launch_bounds__(256) void k_wt(const void* src, u16* dst, int R, int C, const int* flag) {
  int isbf = *flag;
  __shared__ u16 t[32][33];
  long long base = (long long)blockIdx.z * R * C;
  int c0 = blockIdx.x * 32, r0 = blockIdx.y * 32;
  int tx = threadIdx.x & 31, ty = threadIdx.x >> 5;
#pragma unroll
  for (int k = 0; k < 4; ++k) {
    int r = r0 + ty + k * 8;
    t[ty + k * 8][tx] = f2bf(ldf(src, base + (long long)r * C + (c0 + tx), isbf));
  }
  __syncthreads();
#pragma unroll
  for (int k = 0; k < 4; ++k) {
    int c = c0 + ty + k * 8;
    dst[base + (long long)c * R + (r0 + tx)] = t[tx][ty + k * 8];
  }
}

// ---------------- bbox cosine-sim + softmax (bf16 out) ----------------
__global__ __launch_bounds__(256) void k_bboxsim(const void* bbox, const int* flag, u16* sim) {
  int isbf = *flag;
  int b = blockIdx.x >> 8, i = blockIdx.x & 255;
  int j = threadIdx.x;
  long long base = (long long)b * LXc * 4;
  float a[4], c[4];
#pragma unroll
  for (int t = 0; t < 4; ++t) {
    a[t] = ldf(bbox, base + (long long)i * 4 + t, isbf);
    c[t] = ldf(bbox, base + (long long)j * 4 + t, isbf);
  }
  float dot = a[0]*c[0] + a[1]*c[1] + a[2]*c[2] + a[3]*c[3];
  float na  = sqrtf(a[0]*a[0] + a[1]*a[1] + a[2]*a[2] + a[3]*a[3]);
  float ncn = sqrtf(c[0]*c[0] + c[1]*c[1] + c[2]*c[2] + c[3]*c[3]);
  float v = dot / (na * ncn);
  __shared__ float r1[4], r2[4];
  float m = v;
  for (int o = 32; o; o >>= 1) m = fmaxf(m, __shfl_xor(m, o));
  if ((threadIdx.x & 63) == 0) r1[threadIdx.x >> 6] = m;
  __syncthreads();
  m = fmaxf(fmaxf(r1[0], r1[1]), fmaxf(r1[2], r1[3]));
  float e = __expf(v - m);
  float s = e;
  for (int o = 32; o; o >>= 1) s += __shfl_xor(s, o);
  if ((threadIdx.x & 63) == 0) r2[threadIdx.x >> 6] = s;
  __syncthreads();
  s = r2[0] + r2[1] + r2[2] + r2[3];
  sim[((long long)b * LXc + i) * LXc + j] = f2bf(e / s);
}

// ---------------- in-place bf16 row softmax ----------------
__global__ __launch_bounds__(256) void k_softmax2(u16* S, int Lk, long long nrows) {
  long long row = (long long)blockIdx.x * 4 + (threadIdx.x >> 6);
  int lane = threadIdx.x & 63;
  if (row >= nrows) return;
  u16* r = S + row * Lk;
  int nv = Lk >> 6;
  float v[4];
  float mx = -3.0e38f;
  for (int i = 0; i < nv; ++i) { v[i] = bf2f(r[i * 64 + lane]); mx = fmaxf(mx, v[i]); }
  for (int o = 32; o; o >>= 1) mx = fmaxf(mx, __shfl_xor(mx, o));
  float s = 0.f;
  for (int i = 0; i < nv; ++i) { v[i] = __expf(v[i] - mx); s += v[i]; }
  for (int o = 32; o; o >>= 1) s += __shfl_xor(s, o);
  float inv = 1.0f / s;
  for (int i = 0; i < nv; ++i) r[i * 64 + lane] = f2bf(v[i] * inv);
}

// ---------------- residual + layernorm -> f32 cur + bf16 mirror ----------------
__global__ __launch_bounds__(256) void k_lnres2(float* cur, u16* curb, const float* delta,
                                                const void* g, long long gOff,
                                                const void* bb, long long bOff,
                                                const int* flag) {
  int isbf = *flag;
  long long row = blockIdx.x;
  float* xr = cur + row * Dc;
  const float* dr = delta + row * Dc;
  int t = threadIdx.x;
  float v[3];
  float s = 0.f;
#pragma unroll
  for (int i = 0; i < 3; ++i) { int c = t + i * 256; v[i] = xr[c] + dr[c]; s += v[i]; }
  __shared__ float r1[4], r2[4];
  for (int o = 32; o; o >>= 1) s += __shfl_xor(s, o);
  if ((t & 63) == 0) r1[t >> 6] = s;
  __syncthreads();
  float mean = (r1[0] + r1[1] + r1[2] + r1[3]) * (1.0f / 768.0f);
  float s2 = 0.f;
#pragma unroll
  for (int i = 0; i < 3; ++i) { float d = v[i] - mean; s2 += d * d; }
  for (int o = 32; o; o >>= 1) s2 += __shfl_xor(s2, o);
  if ((t & 63) == 0) r2[t >> 6] = s2;
  __syncthreads();
  float var = (r2[0] + r2[1] + r2[2] + r2[3]) * (1.0f / 768.0f);
  float rstd = rsqrtf(var + 1e-6f);
#pragma unroll
  for (int i = 0; i < 3; ++i) {
    int c = t + i * 256;
    float o = ldf(g, gOff + c, isbf) * (v[i] - mean) * rstd + ldf(bb, bOff + c, isbf);
    xr[c] = o;
    curb[row * Dc + c] = f2bf(o);
  }
}

// ---------------- bf16 MFMA GEMM, global_load_lds staging (m97 structure) ----------------
// C = act(scale * A @ W^T + bias); A:[M][K] bf16 lda; W:[N][K] bf16 ldw.
// batched: z -> (zb = z/Hdim, zh = z%Hdim).
// MODE 0: bf16 C[row][col] (ldc, sCb, sCh), optional relu
// MODE 1: f32  C[row][col]
// MODE 2: bf16 vT store: addr = ((row/Lseq)*768 + col)*Lseq + row%Lseq
// MODE 3: bf16 transposed: addr = zb*sCb + zh*sCh + col*ldc + row
struct G2 {
  const u16* A; long long lda, sAb, sAh;
  const u16* W; long long ldw, sWb, sWh;
  const float* bias; long long bOff;
  void* C; long long ldc, sCb, sCh;
  int Hdim; float scale; int relu; int Lseq;
};

template<int BM, int BN, int MODE>
__global__ __launch_bounds__(256, 2) void gemm2(G2 p, int M, int N, int K) {
  constexpr int BK = 64;
  __shared__ __align__(16) u16 Al[BM * BK];
  __shared__ __align__(16) u16 Bl[BN * BK];
  const int tid = threadIdx.x, wid = tid >> 6, lane = tid & 63;
  const int z = blockIdx.z, zb = z / p.Hdim, zh = z % p.Hdim;
  const u16* A = p.A + (long long)zb * p.sAb + (long long)zh * p.sAh;
  const u16* W = p.W + (long long)zb * p.sWb + (long long)zh * p.sWh;
  const int m0 = blockIdx.y * BM, n0 = blockIdx.x * BN;
  const int wr = wid >> 1, wc = wid & 1;
  constexpr int FM = BM / 32, FN = BN / 32;
  f32x4 acc[FM][FN] = {};
  const int lr = lane >> 3;          // row within 8-row chunk
  const int lo = (lane & 7) * 16;    // byte offset within 128B row

  for (int k0 = 0; k0 < K; k0 += BK) {
#pragma unroll
    for (int i = 0; i < BM / 32; ++i) {
      int chunk = wid * (BM / 32) + i;
      int row = chunk * 8 + lr;
      gload16((const char*)(A + (long long)(m0 + row) * p.lda + k0) + lo,
              (char*)Al + chunk * 1024);
    }
#pragma unroll
    for (int i = 0; i < BN / 32; ++i) {
      int chunk = wid * (BN / 32) + i;
      int row = chunk * 8 + lr;
      gload16((const char*)(W + (long long)(n0 + row) * p.ldw + k0) + lo,
              (char*)Bl + chunk * 1024);
    }
    __syncthreads();
#pragma unroll
    for (int ks = 0; ks < 2; ++ks) {
      s16x8 af[FM], bfr[FN];
      const int kc = ks * 32 + (lane >> 4) * 8;
      const int rl = lane & 15;
#pragma unroll
      for (int i = 0; i < FM; ++i) af[i]  = *(const s16x8*)&Al[(wr * (BM / 2) + i * 16 + rl) * BK + kc];
#pragma unroll
      for (int j = 0; j < FN; ++j) bfr[j] = *(const s16x8*)&Bl[(wc * (BN / 2) + j * 16 + rl) * BK + kc];
#pragma unroll
      for (int i = 0; i < FM; ++i)
#pragma unroll
        for (int j = 0; j < FN; ++j)
          acc[i][j] = __builtin_amdgcn_mfma_f32_16x16x32_bf16(af[i], bfr[j], acc[i][j], 0, 0, 0);
    }
    __syncthreads();
  }

#pragma unroll
  for (int j = 0; j < FN; ++j) {
    int col = n0 + wc * (BN / 2) + j * 16 + (lane & 15);
    float bv = p.bias ? p.bias[p.bOff + col] : 0.f;
#pragma unroll
    for (int i = 0; i < FM; ++i) {
      int row0 = m0 + wr * (BM / 2) + i * 16 + (lane >> 4) * 4;
      if (MODE == 0) {
        u16* C = (u16*)p.C + (long long)zb * p.sCb + (long long)zh * p.sCh;
#pragma unroll
        for (int e = 0; e < 4; ++e) {
          float v = acc[i][j][e] * p.scale + bv;
          if (p.relu) v = fmaxf(v, 0.f);
          C[(long long)(row0 + e) * p.ldc + col] = f2bf(v);
        }
      } else if (MODE == 1) {
        float* C = (float*)p.C + (long long)zb * p.sCb + (long long)zh * p.sCh;
#pragma unroll
        for (int e = 0; e < 4; ++e)
          C[(long long)(row0 + e) * p.ldc + col] = acc[i][j][e] * p.scale + bv;
      } else if (MODE == 2) {
        u16* C = (u16*)p.C;
        int b = row0 / p.Lseq, l = row0 % p.Lseq;
        union { u16 u[4]; uint2 d; } pk;
#pragma unroll
        for (int e = 0; e < 4; ++e) pk.u[e] = f2bf(acc[i][j][e] * p.scale + bv);
        *(uint2*)&C[((long long)b * Dc + col) * p.Lseq + l] = pk.d;
      } else {
        u16* C = (u16*)p.C + (long long)zb * p.sCb + (long long)zh * p.sCh;
        union { u16 u[4]; uint2 d; } pk;
#pragma unroll
        for (int e = 0; e < 4; ++e) pk.u[e] = f2bf(acc[i][j][e] * p.scale + bv);
        *(uint2*)&C[(long long)col * p.ldc + row0] = pk.d;
      }
    }
  }
}

// ---------------- launch helpers ----------------
template<int BM, int BN, int MODE>
static void run_gemm(const G2& p, int M, int N, int K, int nz, hipStream_t st) {
  dim3 grid(N / BN, M / BM, nz);
  gemm2<BM, BN, MODE><<<grid, 256, 0, st>>>(p, M, N, K);
}

extern "C" void kernel_launch(void* const* d_in, const int* in_sizes, int n_in,
                              void* d_out, int out_size, void* d_ws, size_t ws_size,
                              hipStream_t stream) {
  const void* y_in  = d_in[0];
  const void* x_in  = d_in[1];
  const void* bbox  = d_in[5];
  const void* enc_aw = d_in[6];  const void* enc_ab = d_in[7];
  const void* enc_w1 = d_in[8];  const void* enc_b1 = d_in[9];
  const void* enc_w2 = d_in[10]; const void* enc_b2 = d_in[11];
  const void* enc_lg = d_in[12]; const void* enc_lb = d_in[13];
  const void* dec_aw = d_in[14]; const void* dec_ab = d_in[15];
  const void* dec_w1 = d_in[16]; const void* dec_b1 = d_in[17];
  const void* dec_w2 = d_in[18]; const void* dec_b2 = d_in[19];
  const void* dec_lg = d_in[20]; const void* dec_lb = d_in[21];

  // ---- ws layout ----
  char* base = (char*)d_ws;
  size_t off = 0;
  auto alloc = [&](size_t bytes) { void* p = base + off; off = (off + bytes + 255) & ~(size_t)255; return p; };
  int*  flag = (int*)alloc(256);
  // transposed bf16 weights
  const long long DD = (long long)Dc * Dc;        // 589824
  const long long DF = (long long)Dc * FFc;       // 2359296
  u16* WencA  = (u16*)alloc(24 * DD * 2);
  u16* WencW1 = (u16*)alloc(6 * DF * 2);
  u16* WencW2 = (u16*)alloc(6 * DF * 2);
  u16* WdecA  = (u16*)alloc(48 * DD * 2);
  u16* WdecW1 = (u16*)alloc(6 * DF * 2);
  u16* WdecW2 = (u16*)alloc(6 * DF * 2);
  // f32 biases
  float* BencA  = (float*)alloc(24 * Dc * 4);
  float* BencW1 = (float*)alloc(6 * FFc * 4);
  float* BencW2 = (float*)alloc(6 * Dc * 4);
  float* BdecA  = (float*)alloc(48 * Dc * 4);
  float* BdecW1 = (float*)alloc(6 * FFc * 4);
  float* BdecW2 = (float*)alloc(6 * Dc * 4);
  // activations
  const long long NYt = (long long)NB * LYc * Dc;     // 3,145,728
  const long long NXt = (long long)NB * LXc * Dc;     // 6,291,456
  float* cur_y  = (float*)alloc(NYt * 4);
  float* cur_x  = (float*)alloc(NXt * 4);
  u16*   curb_y = (u16*)alloc(NYt * 2);
  u16*   curb_x = (u16*)alloc(NXt * 2);
  u16*   simb   = (u16*)alloc((long long)NB * LXc * LXc * 2);
  u16*   qbf    = (u16*)alloc(NXt * 2);
  u16*   kbf    = (u16*)alloc(NXt * 2);
  u16*   vT     = (u16*)alloc(NXt * 2);
  float* delta  = (float*)alloc(NXt * 4);
  u16*   aoT    = (u16*)alloc(NXt * 2);
  u16*   ao2    = (u16*)alloc(NXt * 2);
  u16*   scores = (u16*)alloc((long long)NB * NH * LXc * LXc * 2);  // also ffn-mid

  // ---- prep ----
  k_detect<<<1, 64, 0, stream>>>((const u16*)y_in, flag);
  k_ingest2<<<1024, 256, 0, stream>>>(y_in, cur_y, curb_y, NYt, flag);
  k_ingest2<<<1024, 256, 0, stream>>>(x_in, cur_x, curb_x, NXt, flag);
  k_bboxsim<<<NB * LXc, 256, 0, stream>>>(bbox, flag, simb);
  k_wt<<<dim3(Dc/32, Dc/32, 24), 256, 0, stream>>>(enc_aw, WencA, Dc, Dc, flag);
  k_wt<<<dim3(FFc/32, Dc/32, 6), 256, 0, stream>>>(enc_w1, WencW1, Dc, FFc, flag);
  k_wt<<<dim3(Dc/32, FFc/32, 6), 256, 0, stream>>>(enc_w2, WencW2, FFc, Dc, flag);
  k_wt<<<dim3(Dc/32, Dc/32, 48), 256, 0, stream>>>(dec_aw, WdecA, Dc, Dc, flag);
  k_wt<<<dim3(FFc/32, Dc/32, 6), 256, 0, stream>>>(dec_w1, WdecW1, Dc, FFc, flag);
  k_wt<<<dim3(Dc/32, FFc/32, 6), 256, 0, stream>>>(dec_w2, WdecW2, FFc, Dc, flag);
  k_cvt<<<32, 256, 0, stream>>>(enc_ab, BencA, 24 * Dc, flag);
  k_cvt<<<32, 256, 0, stream>>>(enc_b1, BencW1, 6 * FFc, flag);
  k_cvt<<<32, 256, 0, stream>>>(enc_b2, BencW2, 6 * Dc, flag);
  k_cvt<<<32, 256, 0, stream>>>(dec_ab, BdecA, 48 * Dc, flag);
  k_cvt<<<32, 256, 0, stream>>>(dec_b1, BdecW1, 6 * FFc, flag);
  k_cvt<<<32, 256, 0, stream>>>(dec_b2, BdecW2, 6 * Dc, flag);

  // ---- helpers ----
  auto proj_b16 = [&](const u16* A, int M, const u16* Wt, long long wOff,
                      const float* bias, long long bOff, u16* C, int N, int K,
                      int relu) {
    G2 p{}; p.A = A; p.lda = K; p.W = Wt + wOff; p.ldw = K;
    p.bias = bias; p.bOff = bOff; p.C = C; p.ldc = N;
    p.Hdim = 1; p.scale = 1.f; p.relu = relu;
    run_gemm<128, 128, 0>(p, M, N, K, 1, stream);
  };
  auto proj_f32 = [&](const u16* A, int M, const u16* Wt, long long wOff,
                      const float* bias, long long bOff, float* C, int N, int K) {
    G2 p{}; p.A = A; p.lda = K; p.W = Wt + wOff; p.ldw = K;
    p.bias = bias; p.bOff = bOff; p.C = C; p.ldc = N;
    p.Hdim = 1; p.scale = 1.f;
    run_gemm<128, 128, 1>(p, M, N, K, 1, stream);
  };
  auto proj_vT = [&](const u16* A, int M, const u16* Wt, long long wOff,
                     const float* bias, long long bOff, int Lseq) {
    G2 p{}; p.A = A; p.lda = Dc; p.W = Wt + wOff; p.ldw = Dc;
    p.bias = bias; p.bOff = bOff; p.C = vT;
    p.Hdim = 1; p.scale = 1.f; p.Lseq = Lseq;
    run_gemm<128, 128, 2>(p, M, Dc, Dc, 1, stream);
  };
  auto g_scores = [&](const u16* Q, int Lq, const u16* Kb, int Lk) {
    G2 p{}; p.A = Q; p.lda = Dc; p.sAb = (long long)Lq * Dc; p.sAh = 64;
    p.W = Kb; p.ldw = Dc; p.sWb = (long long)Lk * Dc; p.sWh = 64;
    p.C = scores; p.ldc = Lk; p.sCb = (long long)NH * Lq * Lk; p.sCh = (long long)Lq * Lk;
    p.Hdim = NH; p.scale = 0.125f;
    run_gemm<128, 128, 0>(p, Lq, Lk, 64, NB * NH, stream);
  };
  auto g_pv = [&](int Lq, int Lk, int dec) {
    G2 p{}; p.A = scores; p.lda = Lk; p.sAb = (long long)NH * Lq * Lk; p.sAh = (long long)Lq * Lk;
    p.W = vT; p.ldw = Lk; p.sWb = (long long)Dc * Lk; p.sWh = (long long)64 * Lk;
    p.Hdim = NH; p.scale = 1.f;
    if (dec) {  // store transposed into aoT[b][768][LXc]
      p.C = aoT; p.ldc = LXc; p.sCb = (long long)Dc * LXc; p.sCh = (long long)64 * LXc;
      run_gemm<128, 64, 3>(p, Lq, 64, Lk, NB * NH, stream);
    } else {    // store normal into ao2[b*LYc+q][768] at head cols
      p.C = ao2; p.ldc = Dc; p.sCb = (long long)LYc * Dc; p.sCh = 64;
      run_gemm<128, 64, 0>(p, Lq, 64, Lk, NB * NH, stream);
    }
  };
  auto g_rel = [&]() {  // ao2[b][q][d] = sum_p sim[b][q][p] * aoT[b][d][p]
    G2 p{}; p.A = simb; p.lda = LXc; p.sAb = (long long)LXc * LXc;
    p.W = aoT; p.ldw = LXc; p.sWb = (long long)Dc * LXc;
    p.C = ao2; p.ldc = Dc; p.sCb = (long long)LXc * Dc;
    p.Hdim = 1; p.scale = 1.f;
    run_gemm<128, 128, 0>(p, LXc, Dc, LXc, NB, stream);
  };

  // ---- encoder ----
  for (int i = 0; i < 6; ++i) {
    int M = NB * LYc;
    long long wo = (long long)i * 4 * DD, bo = (long long)i * 4 * Dc;
    proj_b16(curb_y, M, WencA, wo + 0 * DD, BencA, bo + 0 * Dc, qbf, Dc, Dc, 0);
    proj_b16(curb_y, M, WencA, wo + 1 * DD, BencA, bo + 1 * Dc, kbf, Dc, Dc, 0);
    proj_vT (curb_y, M, WencA, wo + 2 * DD, BencA, bo + 2 * Dc, LYc);
    g_scores(qbf, LYc, kbf, LYc);
    k_softmax2<<<(NB * NH * LYc) / 4, 256, 0, stream>>>(scores, LYc, (long long)NB * NH * LYc);
    g_pv(LYc, LYc, 0);
    proj_f32(ao2, M, WencA, wo + 3 * DD, BencA, bo + 3 * Dc, delta, Dc, Dc);
    k_lnres2<<<M, 256, 0, stream>>>(cur_y, curb_y, delta, enc_lg, (long long)(i*2+0)*Dc, enc_lb, (long long)(i*2+0)*Dc, flag);
    proj_b16(curb_y, M, WencW1, (long long)i * DF, BencW1, (long long)i * FFc, scores, FFc, Dc, 1);
    proj_f32(scores, M, WencW2, (long long)i * DF, BencW2, (long long)i * Dc, delta, Dc, FFc);
    k_lnres2<<<M, 256, 0, stream>>>(cur_y, curb_y, delta, enc_lg, (long long)(i*2+1)*Dc, enc_lb, (long long)(i*2+1)*Dc, flag);
  }

  // ---- decoder ----
  for (int i = 0; i < 6; ++i) {
    int M = NB * LXc;
    for (int a = 0; a < 2; ++a) {  // a=0 self (x,x), a=1 cross (q from x, k/v from y)
      long long wo = (long long)(i * 2 + a) * 4 * DD;
      long long bo = (long long)(i * 2 + a) * 4 * Dc;
      const u16* kvsrc = a ? curb_y : curb_x;
      int Mk = a ? NB * LYc : NB * LXc;
      int Lk = a ? LYc : LXc;
      proj_b16(curb_x, M, WdecA, wo + 0 * DD, BdecA, bo + 0 * Dc, qbf, Dc, Dc, 0);
      proj_b16(kvsrc, Mk, WdecA, wo + 1 * DD, BdecA, bo + 1 * Dc, kbf, Dc, Dc, 0);
      proj_vT (kvsrc, Mk, WdecA, wo + 2 * DD, BdecA, bo + 2 * Dc, Lk);
      g_scores(qbf, LXc, kbf, Lk);
      k_softmax2<<<(NB * NH * LXc) / 4, 256, 0, stream>>>(scores, Lk, (long long)NB * NH * LXc);
      g_pv(LXc, Lk, 1);
      g_rel();
      proj_f32(ao2, M, WdecA, wo + 3 * DD, BdecA, bo + 3 * Dc, delta, Dc, Dc);
      k_lnres2<<<M, 256, 0, stream>>>(cur_x, curb_x, delta, dec_lg, (long long)(i*3+a)*Dc, dec_lb, (long long)(i*3+a)*Dc, flag);
    }
    proj_b16(curb_x, M, WdecW1, (long long)i * DF, BdecW1, (long long)i * FFc, scores, FFc, Dc, 1);
    proj_f32(scores, M, WdecW2, (long long)i * DF, BdecW2, (long long)i * Dc, delta, Dc, FFc);
    k_lnres2<<<M, 256, 0, stream>>>(cur_x, curb_x, delta, dec_lg, (long long)(i*3+2)*Dc, dec_lb, (long long)(i*3+2)*Dc, flag);
  }

  k_emit<<<2048, 256, 0, stream>>>(cur_y, cur_x, d_out, flag, NYt, NYt + NXt);
}

// Round 3
// 4433.894 us; speedup vs baseline: 3.3172x; 1.1229x over previous
//
#include <hip/hip_runtime.h>

#define DEV __device__ __forceinline__

constexpr int NB  = 32;
constexpr int LXc = 256;
constexpr int LYc = 128;
constexpr int Dc  = 768;
constexpr int NH  = 12;
constexpr int FFc = 3072;

typedef unsigned short u16;
typedef float f32x4 __attribute__((ext_vector_type(4)));
typedef short s16x8 __attribute__((ext_vector_type(8)));

DEV u16 f2bf(float f) {
  unsigned u = __float_as_uint(f);
  u += 0x7FFFu + ((u >> 16) & 1u);
  return (u16)(u >> 16);
}
DEV float bf2f(u16 w) { return __uint_as_float(((unsigned)w) << 16); }
DEV float ldf(const void* p, long long i, int isbf) {
  return isbf ? bf2f(((const u16*)p)[i]) : ((const float*)p)[i];
}

DEV void gload16(const void* g, void* l) {
  __builtin_amdgcn_global_load_lds(
      (const __attribute__((address_space(1))) void*)g,
      (__attribute__((address_space(3))) void*)l, 16, 0, 0);
}

// ---------------- dtype detection ----------------
__global__ void k_detect(const u16* y, int* flag) {
  if (threadIdx.x == 0) {
    int cnt = 0;
    for (int i = 0; i < 256; ++i) {
      u16 w = y[i];
      int e = (w >> 7) & 0xFF;
      if (e == 0 || (e >= 112 && e <= 140)) cnt++;
    }
    *flag = (cnt >= 200) ? 1 : 0;
  }
}

// ---------------- ingest: raw -> f32 + bf16 mirror ----------------
__global__ void k_ingest2(const void* src, float* dst, u16* dstb, long long n, const int* flag) {
  int isbf = *flag;
  long long i = (long long)blockIdx.x * blockDim.x + threadIdx.x;
  long long st = (long long)gridDim.x * blockDim.x;
  for (; i < n; i += st) { float v = ldf(src, i, isbf); dst[i] = v; dstb[i] = f2bf(v); }
}

__global__ void k_cvt(const void* src, float* dst, long long n, const int* flag) {
  int isbf = *flag;
  long long i = (long long)blockIdx.x * blockDim.x + threadIdx.x;
  long long st = (long long)gridDim.x * blockDim.x;
  for (; i < n; i += st) dst[i] = ldf(src, i, isbf);
}

__global__ void k_emit(const float* ybuf, const float* xbuf, void* out,
                       const int* flag, long long ny, long long nt) {
  int isbf = *flag;
  long long i = (long long)blockIdx.x * blockDim.x + threadIdx.x;
  long long st = (long long)gridDim.x * blockDim.x;
  for (; i < nt; i += st) {
    float v = (i < ny) ? ybuf[i] : xbuf[i - ny];
    if (isbf) ((u16*)out)[i] = f2bf(v);
    else      ((float*)out)[i] = v;
  }
}

// ---------------- weight transpose+convert: [R][C] raw -> [C][R] bf16 ----------------
__global__ __launch_bounds__(256) void k_wt(const void* src, u16* dst, int R, int C, const int* flag) {
  int isbf = *flag;
  __shared__ u16 t[32][33];
  long long base = (long long)blockIdx.z * R * C;
  int c0 = blockIdx.x * 32, r0 = blockIdx.y * 32;
  int tx = threadIdx.x & 31, ty = threadIdx.x >> 5;
#pragma unroll
  for (int k = 0; k < 4; ++k) {
    int r = r0 + ty + k * 8;
    t[ty + k * 8][tx] = f2bf(ldf(src, base + (long long)r * C + (c0 + tx), isbf));
  }
  __syncthreads();
#pragma unroll
  for (int k = 0; k < 4; ++k) {
    int c = c0 + ty + k * 8;
    dst[base + (long long)c * R + (r0 + tx)] = t[tx][ty + k * 8];
  }
}

// ---------------- bbox cosine-sim + softmax (bf16 out) ----------------
__global__ __launch_bounds__(256) void k_bboxsim(const void* bbox, const int* flag, u16* sim) {
  int isbf = *flag;
  int b = blockIdx.x >> 8, i = blockIdx.x & 255;
  int j = threadIdx.x;
  long long base = (long long)b * LXc * 4;
  float a[4], c[4];
#pragma unroll
  for (int t = 0; t < 4; ++t) {
    a[t] = ldf(bbox, base + (long long)i * 4 + t, isbf);
    c[t] = ldf(bbox, base + (long long)j * 4 + t, isbf);
  }
  float dot = a[0]*c[0] + a[1]*c[1] + a[2]*c[2] + a[3]*c[3];
  float na  = sqrtf(a[0]*a[0] + a[1]*a[1] + a[2]*a[2] + a[3]*a[3]);
  float ncn = sqrtf(c[0]*c[0] + c[1]*c[1] + c[2]*c[2] + c[3]*c[3]);
  float v = dot / (na * ncn);
  __shared__ float r1[4], r2[4];
  float m = v;
  for (int o = 32; o; o >>= 1) m = fmaxf(m, __shfl_xor(m, o));
  if ((threadIdx.x & 63) == 0) r1[threadIdx.x >> 6] = m;
  __syncthreads();
  m = fmaxf(fmaxf(r1[0], r1[1]), fmaxf(r1[2], r1[3]));
  float e = __expf(v - m);
  float s = e;
  for (int o = 32; o; o >>= 1) s += __shfl_xor(s, o);
  if ((threadIdx.x & 63) == 0) r2[threadIdx.x >> 6] = s;
  __syncthreads();
  s = r2[0] + r2[1] + r2[2] + r2[3];
  sim[((long long)b * LXc + i) * LXc + j] = f2bf(e / s);
}

// ---------------- in-place bf16 row softmax ----------------
__global__ __launch_bounds__(256) void k_softmax2(u16* S, int Lk, long long nrows) {
  long long row = (long long)blockIdx.x * 4 + (threadIdx.x >> 6);
  int lane = threadIdx.x & 63;
  if (row >= nrows) return;
  u16* r = S + row * Lk;
  int nv = Lk >> 6;
  float v[4];
  float mx = -3.0e38f;
  for (int i = 0; i < nv; ++i) { v[i] = bf2f(r[i * 64 + lane]); mx = fmaxf(mx, v[i]); }
  for (int o = 32; o; o >>= 1) mx = fmaxf(mx, __shfl_xor(mx, o));
  float s = 0.f;
  for (int i = 0; i < nv; ++i) { v[i] = __expf(v[i] - mx); s += v[i]; }
  for (int o = 32; o; o >>= 1) s += __shfl_xor(s, o);
  float inv = 1.0f / s;
  for (int i = 0; i < nv; ++i) r[i * 64 + lane] = f2bf(v[i] * inv);
}

// ---------------- residual + layernorm -> f32 cur + bf16 mirror ----------------
__global__ __launch_bounds__(256) void k_lnres2(float* cur, u16* curb, const float* delta,
                                                const void* g, long long gOff,
                                                const void* bb, long long bOff,
                                                const int* flag) {
  int isbf = *flag;
  long long row = blockIdx.x;
  float* xr = cur + row * Dc;
  const float* dr = delta + row * Dc;
  int t = threadIdx.x;
  float v[3];
  float s = 0.f;
#pragma unroll
  for (int i = 0; i < 3; ++i) { int c = t + i * 256; v[i] = xr[c] + dr[c]; s += v[i]; }
  __shared__ float r1[4], r2[4];
  for (int o = 32; o; o >>= 1) s += __shfl_xor(s, o);
  if ((t & 63) == 0) r1[t >> 6] = s;
  __syncthreads();
  float mean = (r1[0] + r1[1] + r1[2] + r1[3]) * (1.0f / 768.0f);
  float s2 = 0.f;
#pragma unroll
  for (int i = 0; i < 3; ++i) { float d = v[i] - mean; s2 += d * d; }
  for (int o = 32; o; o >>= 1) s2 += __shfl_xor(s2, o);
  if ((t & 63) == 0) r2[t >> 6] = s2;
  __syncthreads();
  float var = (r2[0] + r2[1] + r2[2] + r2[3]) * (1.0f / 768.0f);
  float rstd = rsqrtf(var + 1e-6f);
#pragma unroll
  for (int i = 0; i < 3; ++i) {
    int c = t + i * 256;
    float o = ldf(g, gOff + c, isbf) * (v[i] - mean) * rstd + ldf(bb, bOff + c, isbf);
    xr[c] = o;
    curb[row * Dc + c] = f2bf(o);
  }
}

// ---------------- bf16 MFMA GEMM, global_load_lds staging ----------------
// C = act(scale * A @ W^T + bias); A:[M][K] bf16 lda; W:[N][K] bf16 ldw.
// batched: z -> (zb = z/Hdim, zh = z%Hdim).
// MODE 0: bf16 C[row][col], optional relu
// MODE 1: f32  C[row][col]
// MODE 2: bf16 vT store: addr = ((row/Lseq)*768 + col)*Lseq + row%Lseq
// MODE 3: bf16 transposed: addr = col*ldc + row
// MODE 4: segment-routed QKV: seg = n0/768 -> {C, Ck, Cv}; seg==vSeg stores vT-style
struct G2 {
  const u16* A; long long lda, sAb, sAh;
  const u16* W; long long ldw, sWb, sWh;
  const float* bias; long long bOff;
  void* C; long long ldc, sCb, sCh;
  void* Ck; void* Cv; int vSeg;
  int Hdim; float scale; int relu; int Lseq;
};

template<int BM, int BN, int MODE>
__global__ __launch_bounds__(256, 2) void gemm2(G2 p, int M, int N, int K) {
  constexpr int BK = 64;
  __shared__ __align__(16) u16 Al[BM * BK];
  __shared__ __align__(16) u16 Bl[BN * BK];
  const int tid = threadIdx.x, wid = tid >> 6, lane = tid & 63;
  const int z = blockIdx.z, zb = z / p.Hdim, zh = z % p.Hdim;
  // XCD-aware bijective swizzle (m204) for single-slice grids
  int bx = blockIdx.x, by = blockIdx.y;
  if (gridDim.z == 1) {
    int gx = gridDim.x, nwg = gx * gridDim.y;
    int orig = by * gx + bx;
    int q = nwg >> 3, r = nwg & 7, xcd = orig & 7, lin = orig >> 3;
    int wg = (xcd < r ? xcd * (q + 1) : r * (q + 1) + (xcd - r) * q) + lin;
    bx = wg % gx; by = wg / gx;
  }
  const u16* A = p.A + (long long)zb * p.sAb + (long long)zh * p.sAh;
  const u16* W = p.W + (long long)zb * p.sWb + (long long)zh * p.sWh;
  const int m0 = by * BM, n0 = bx * BN;
  const int wr = wid >> 1, wc = wid & 1;
  constexpr int FM = BM / 32, FN = BN / 32;
  f32x4 acc[FM][FN] = {};
  const int lr = lane >> 3;
  const int lo = (lane & 7) * 16;

  for (int k0 = 0; k0 < K; k0 += BK) {
#pragma unroll
    for (int i = 0; i < BM / 32; ++i) {
      int chunk = wid * (BM / 32) + i;
      int row = chunk * 8 + lr;
      gload16((const char*)(A + (long long)(m0 + row) * p.lda + k0) + lo,
              (char*)Al + chunk * 1024);
    }
#pragma unroll
    for (int i = 0; i < BN / 32; ++i) {
      int chunk = wid * (BN / 32) + i;
      int row = chunk * 8 + lr;
      gload16((const char*)(W + (long long)(n0 + row) * p.ldw + k0) + lo,
              (char*)Bl + chunk * 1024);
    }
    __syncthreads();
#pragma unroll
    for (int ks = 0; ks < 2; ++ks) {
      s16x8 af[FM], bfr[FN];
      const int kc = ks * 32 + (lane >> 4) * 8;
      const int rl = lane & 15;
#pragma unroll
      for (int i = 0; i < FM; ++i) af[i]  = *(const s16x8*)&Al[(wr * (BM / 2) + i * 16 + rl) * BK + kc];
#pragma unroll
      for (int j = 0; j < FN; ++j) bfr[j] = *(const s16x8*)&Bl[(wc * (BN / 2) + j * 16 + rl) * BK + kc];
#pragma unroll
      for (int i = 0; i < FM; ++i)
#pragma unroll
        for (int j = 0; j < FN; ++j)
          acc[i][j] = __builtin_amdgcn_mfma_f32_16x16x32_bf16(af[i], bfr[j], acc[i][j], 0, 0, 0);
    }
    __syncthreads();
  }

  const int seg = (MODE == 4) ? (n0 / 768) : 0;
#pragma unroll
  for (int j = 0; j < FN; ++j) {
    int col = n0 + wc * (BN / 2) + j * 16 + (lane & 15);
    float bv = p.bias ? p.bias[p.bOff + col] : 0.f;
#pragma unroll
    for (int i = 0; i < FM; ++i) {
      int row0 = m0 + wr * (BM / 2) + i * 16 + (lane >> 4) * 4;
      if (MODE == 0) {
        u16* C = (u16*)p.C + (long long)zb * p.sCb + (long long)zh * p.sCh;
#pragma unroll
        for (int e = 0; e < 4; ++e) {
          float v = acc[i][j][e] * p.scale + bv;
          if (p.relu) v = fmaxf(v, 0.f);
          C[(long long)(row0 + e) * p.ldc + col] = f2bf(v);
        }
      } else if (MODE == 1) {
        float* C = (float*)p.C + (long long)zb * p.sCb + (long long)zh * p.sCh;
#pragma unroll
        for (int e = 0; e < 4; ++e)
          C[(long long)(row0 + e) * p.ldc + col] = acc[i][j][e] * p.scale + bv;
      } else if (MODE == 2) {
        u16* C = (u16*)p.C;
        int b = row0 / p.Lseq, l = row0 % p.Lseq;
        union { u16 u[4]; uint2 d; } pk;
#pragma unroll
        for (int e = 0; e < 4; ++e) pk.u[e] = f2bf(acc[i][j][e] * p.scale + bv);
        *(uint2*)&C[((long long)b * Dc + col) * p.Lseq + l] = pk.d;
      } else if (MODE == 3) {
        u16* C = (u16*)p.C + (long long)zb * p.sCb + (long long)zh * p.sCh;
        union { u16 u[4]; uint2 d; } pk;
#pragma unroll
        for (int e = 0; e < 4; ++e) pk.u[e] = f2bf(acc[i][j][e] * p.scale + bv);
        *(uint2*)&C[(long long)col * p.ldc + row0] = pk.d;
      } else {  // MODE 4
        u16* outp = seg == 0 ? (u16*)p.C : (seg == 1 ? (u16*)p.Ck : (u16*)p.Cv);
        int c = col - seg * 768;
        if (seg == p.vSeg) {       // V segment: transposed store
          int b = row0 / p.Lseq, l = row0 % p.Lseq;
          union { u16 u[4]; uint2 d; } pk;
#pragma unroll
          for (int e = 0; e < 4; ++e) pk.u[e] = f2bf(acc[i][j][e] + bv);
          *(uint2*)&outp[((long long)b * Dc + c) * p.Lseq + l] = pk.d;
        } else {
#pragma unroll
          for (int e = 0; e < 4; ++e)
            outp[(long long)(row0 + e) * 768 + c] = f2bf(acc[i][j][e] + bv);
        }
      }
    }
  }
}

// ---------------- launch helpers ----------------
template<int BM, int BN, int MODE>
static void run_gemm(const G2& p, int M, int N, int K, int nz, hipStream_t st) {
  dim3 grid(N / BN, M / BM, nz);
  gemm2<BM, BN, MODE><<<grid, 256, 0, st>>>(p, M, N, K);
}

extern "C" void kernel_launch(void* const* d_in, const int* in_sizes, int n_in,
                              void* d_out, int out_size, void* d_ws, size_t ws_size,
                              hipStream_t stream) {
  const void* y_in  = d_in[0];
  const void* x_in  = d_in[1];
  const void* bbox  = d_in[5];
  const void* enc_aw = d_in[6];  const void* enc_ab = d_in[7];
  const void* enc_w1 = d_in[8];  const void* enc_b1 = d_in[9];
  const void* enc_w2 = d_in[10]; const void* enc_b2 = d_in[11];
  const void* enc_lg = d_in[12]; const void* enc_lb = d_in[13];
  const void* dec_aw = d_in[14]; const void* dec_ab = d_in[15];
  const void* dec_w1 = d_in[16]; const void* dec_b1 = d_in[17];
  const void* dec_w2 = d_in[18]; const void* dec_b2 = d_in[19];
  const void* dec_lg = d_in[20]; const void* dec_lb = d_in[21];

  // ---- ws layout ----
  char* base = (char*)d_ws;
  size_t off = 0;
  auto alloc = [&](size_t bytes) { void* p = base + off; off = (off + bytes + 255) & ~(size_t)255; return p; };
  int*  flag = (int*)alloc(256);
  const long long DD = (long long)Dc * Dc;
  const long long DF = (long long)Dc * FFc;
  u16* WencA  = (u16*)alloc(24 * DD * 2);
  u16* WencW1 = (u16*)alloc(6 * DF * 2);
  u16* WencW2 = (u16*)alloc(6 * DF * 2);
  u16* WdecA  = (u16*)alloc(48 * DD * 2);
  u16* WdecW1 = (u16*)alloc(6 * DF * 2);
  u16* WdecW2 = (u16*)alloc(6 * DF * 2);
  float* BencA  = (float*)alloc(24 * Dc * 4);
  float* BencW1 = (float*)alloc(6 * FFc * 4);
  float* BencW2 = (float*)alloc(6 * Dc * 4);
  float* BdecA  = (float*)alloc(48 * Dc * 4);
  float* BdecW1 = (float*)alloc(6 * FFc * 4);
  float* BdecW2 = (float*)alloc(6 * Dc * 4);
  const long long NYt = (long long)NB * LYc * Dc;
  const long long NXt = (long long)NB * LXc * Dc;
  float* cur_y  = (float*)alloc(NYt * 4);
  float* cur_x  = (float*)alloc(NXt * 4);
  u16*   curb_y = (u16*)alloc(NYt * 2);
  u16*   curb_x = (u16*)alloc(NXt * 2);
  u16*   simb   = (u16*)alloc((long long)NB * LXc * LXc * 2);
  u16*   qbf    = (u16*)alloc(NXt * 2);
  u16*   kbf    = (u16*)alloc(NXt * 2);
  u16*   vT     = (u16*)alloc(NXt * 2);
  float* delta  = (float*)alloc(NXt * 4);
  u16*   aoT    = (u16*)alloc(NXt * 2);
  u16*   ao2    = (u16*)alloc(NXt * 2);
  u16*   scores = (u16*)alloc((long long)NB * NH * LXc * LXc * 2);

  // ---- prep ----
  k_detect<<<1, 64, 0, stream>>>((const u16*)y_in, flag);
  k_ingest2<<<1024, 256, 0, stream>>>(y_in, cur_y, curb_y, NYt, flag);
  k_ingest2<<<1024, 256, 0, stream>>>(x_in, cur_x, curb_x, NXt, flag);
  k_bboxsim<<<NB * LXc, 256, 0, stream>>>(bbox, flag, simb);
  k_wt<<<dim3(Dc/32, Dc/32, 24), 256, 0, stream>>>(enc_aw, WencA, Dc, Dc, flag);
  k_wt<<<dim3(FFc/32, Dc/32, 6), 256, 0, stream>>>(enc_w1, WencW1, Dc, FFc, flag);
  k_wt<<<dim3(Dc/32, FFc/32, 6), 256, 0, stream>>>(enc_w2, WencW2, FFc, Dc, flag);
  k_wt<<<dim3(Dc/32, Dc/32, 48), 256, 0, stream>>>(dec_aw, WdecA, Dc, Dc, flag);
  k_wt<<<dim3(FFc/32, Dc/32, 6), 256, 0, stream>>>(dec_w1, WdecW1, Dc, FFc, flag);
  k_wt<<<dim3(Dc/32, FFc/32, 6), 256, 0, stream>>>(dec_w2, WdecW2, FFc, Dc, flag);
  k_cvt<<<32, 256, 0, stream>>>(enc_ab, BencA, 24 * Dc, flag);
  k_cvt<<<32, 256, 0, stream>>>(enc_b1, BencW1, 6 * FFc, flag);
  k_cvt<<<32, 256, 0, stream>>>(enc_b2, BencW2, 6 * Dc, flag);
  k_cvt<<<32, 256, 0, stream>>>(dec_ab, BdecA, 48 * Dc, flag);
  k_cvt<<<32, 256, 0, stream>>>(dec_b1, BdecW1, 6 * FFc, flag);
  k_cvt<<<32, 256, 0, stream>>>(dec_b2, BdecW2, 6 * Dc, flag);

  // ---- helpers ----
  auto proj_qkv = [&](const u16* A, int M, const u16* Wt, long long wOff,
                      const float* bias, long long bOff, int Lseq) {
    G2 p{}; p.A = A; p.lda = Dc; p.W = Wt + wOff; p.ldw = Dc;
    p.bias = bias; p.bOff = bOff;
    p.C = qbf; p.Ck = kbf; p.Cv = vT; p.vSeg = 2;
    p.Hdim = 1; p.scale = 1.f; p.Lseq = Lseq;
    run_gemm<128, 128, 4>(p, M, 3 * Dc, Dc, 1, stream);
  };
  auto proj_kv = [&](const u16* A, int M, const u16* Wt, long long wOff,
                     const float* bias, long long bOff, int Lseq) {
    G2 p{}; p.A = A; p.lda = Dc; p.W = Wt + wOff; p.ldw = Dc;
    p.bias = bias; p.bOff = bOff;
    p.C = kbf; p.Ck = vT; p.vSeg = 1;
    p.Hdim = 1; p.scale = 1.f; p.Lseq = Lseq;
    run_gemm<128, 128, 4>(p, M, 2 * Dc, Dc, 1, stream);
  };
  auto proj_b16 = [&](const u16* A, int M, const u16* Wt, long long wOff,
                      const float* bias, long long bOff, u16* C, int N, int K,
                      int relu) {
    G2 p{}; p.A = A; p.lda = K; p.W = Wt + wOff; p.ldw = K;
    p.bias = bias; p.bOff = bOff; p.C = C; p.ldc = N;
    p.Hdim = 1; p.scale = 1.f; p.relu = relu;
    run_gemm<128, 128, 0>(p, M, N, K, 1, stream);
  };
  auto proj_f32 = [&](const u16* A, int M, const u16* Wt, long long wOff,
                      const float* bias, long long bOff, float* C, int N, int K) {
    G2 p{}; p.A = A; p.lda = K; p.W = Wt + wOff; p.ldw = K;
    p.bias = bias; p.bOff = bOff; p.C = C; p.ldc = N;
    p.Hdim = 1; p.scale = 1.f;
    run_gemm<128, 128, 1>(p, M, N, K, 1, stream);
  };
  auto g_scores = [&](const u16* Q, int Lq, const u16* Kb, int Lk) {
    G2 p{}; p.A = Q; p.lda = Dc; p.sAb = (long long)Lq * Dc; p.sAh = 64;
    p.W = Kb; p.ldw = Dc; p.sWb = (long long)Lk * Dc; p.sWh = 64;
    p.C = scores; p.ldc = Lk; p.sCb = (long long)NH * Lq * Lk; p.sCh = (long long)Lq * Lk;
    p.Hdim = NH; p.scale = 0.125f;
    run_gemm<128, 128, 0>(p, Lq, Lk, 64, NB * NH, stream);
  };
  auto g_pv = [&](int Lq, int Lk, int dec) {
    G2 p{}; p.A = scores; p.lda = Lk; p.sAb = (long long)NH * Lq * Lk; p.sAh = (long long)Lq * Lk;
    p.W = vT; p.ldw = Lk; p.sWb = (long long)Dc * Lk; p.sWh = (long long)64 * Lk;
    p.Hdim = NH; p.scale = 1.f;
    if (dec) {
      p.C = aoT; p.ldc = LXc; p.sCb = (long long)Dc * LXc; p.sCh = (long long)64 * LXc;
      run_gemm<128, 64, 3>(p, Lq, 64, Lk, NB * NH, stream);
    } else {
      p.C = ao2; p.ldc = Dc; p.sCb = (long long)LYc * Dc; p.sCh = 64;
      run_gemm<128, 64, 0>(p, Lq, 64, Lk, NB * NH, stream);
    }
  };
  auto g_rel = [&]() {
    G2 p{}; p.A = simb; p.lda = LXc; p.sAb = (long long)LXc * LXc;
    p.W = aoT; p.ldw = LXc; p.sWb = (long long)Dc * LXc;
    p.C = ao2; p.ldc = Dc; p.sCb = (long long)LXc * Dc;
    p.Hdim = 1; p.scale = 1.f;
    run_gemm<128, 128, 0>(p, LXc, Dc, LXc, NB, stream);
  };

  // ---- encoder ----
  for (int i = 0; i < 6; ++i) {
    int M = NB * LYc;
    long long wo = (long long)i * 4 * DD, bo = (long long)i * 4 * Dc;
    proj_qkv(curb_y, M, WencA, wo, BencA, bo, LYc);
    g_scores(qbf, LYc, kbf, LYc);
    k_softmax2<<<(NB * NH * LYc) / 4, 256, 0, stream>>>(scores, LYc, (long long)NB * NH * LYc);
    g_pv(LYc, LYc, 0);
    proj_f32(ao2, M, WencA, wo + 3 * DD, BencA, bo + 3 * Dc, delta, Dc, Dc);
    k_lnres2<<<M, 256, 0, stream>>>(cur_y, curb_y, delta, enc_lg, (long long)(i*2+0)*Dc, enc_lb, (long long)(i*2+0)*Dc, flag);
    proj_b16(curb_y, M, WencW1, (long long)i * DF, BencW1, (long long)i * FFc, scores, FFc, Dc, 1);
    proj_f32(scores, M, WencW2, (long long)i * DF, BencW2, (long long)i * Dc, delta, Dc, FFc);
    k_lnres2<<<M, 256, 0, stream>>>(cur_y, curb_y, delta, enc_lg, (long long)(i*2+1)*Dc, enc_lb, (long long)(i*2+1)*Dc, flag);
  }

  // ---- decoder ----
  for (int i = 0; i < 6; ++i) {
    int M = NB * LXc;
    for (int a = 0; a < 2; ++a) {
      long long wo = (long long)(i * 2 + a) * 4 * DD;
      long long bo = (long long)(i * 2 + a) * 4 * Dc;
      if (a == 0) {
        proj_qkv(curb_x, M, WdecA, wo, BdecA, bo, LXc);
      } else {
        G2 p{}; p.A = curb_x; p.lda = Dc; p.W = WdecA + wo; p.ldw = Dc;
        p.bias = BdecA; p.bOff = bo; p.C = qbf; p.ldc = Dc;
        p.Hdim = 1; p.scale = 1.f;
        run_gemm<128, 128, 0>(p, M, Dc, Dc, 1, stream);
        proj_kv(curb_y, NB * LYc, WdecA, wo + DD, BdecA, bo + Dc, LYc);
      }
      int Lk = a ? LYc : LXc;
      g_scores(qbf, LXc, kbf, Lk);
      k_softmax2<<<(NB * NH * LXc) / 4, 256, 0, stream>>>(scores, Lk, (long long)NB * NH * LXc);
      g_pv(LXc, Lk, 1);
      g_rel();
      proj_f32(ao2, M, WdecA, wo + 3 * DD, BdecA, bo + 3 * Dc, delta, Dc, Dc);
      k_lnres2<<<M, 256, 0, stream>>>(cur_x, curb_x, delta, dec_lg, (long long)(i*3+a)*Dc, dec_lb, (long long)(i*3+a)*Dc, flag);
    }
    proj_b16(curb_x, M, WdecW1, (long long)i * DF, BdecW1, (long long)i * FFc, scores, FFc, Dc, 1);
    proj_f32(scores, M, WdecW2, (long long)i * DF, BdecW2, (long long)i * Dc, delta, Dc, FFc);
    k_lnres2<<<M, 256, 0, stream>>>(cur_x, curb_x, delta, dec_lg, (long long)(i*3+2)*Dc, dec_lb, (long long)(i*3+2)*Dc, flag);
  }

  k_emit<<<2048, 256, 0, stream>>>(cur_y, cur_x, d_out, flag, NYt, NYt + NXt);
}